// Round 7
// baseline (108.588 us; speedup 1.0000x reference)
//
#include <hip/hip_runtime.h>
#include <math.h>

// Problem constants (fixed by the reference's setup_inputs)
constexpr int B = 2, G = 8, D = 16, H = 256, W = 320;
constexpr int HW = H * W;
constexpr float EPS = 1e-5f;
constexpr int WSTRIDE = 320;   // floats per folded-weight block (P at 0, S at 320)

__device__ __forceinline__ float sigmoidf_(float x) {
    return 1.0f / (1.0f + __expf(-x));
}

__device__ __forceinline__ int reflect_(int i, int n) {
    return i < 0 ? -i : (i >= n ? 2 * n - 2 - i : i);
}

// ---------------------------------------------------------------------------
// k_prep: fold BN (gamma / sqrt(1+eps)) into weights, pack into d_ws.
// Layout per net (stride WSTRIDE): W0f[0:128) W1f[128:256) W2[256:264)
// B0[264:280) B1[280:288) bias2[288].
// ---------------------------------------------------------------------------
__global__ __launch_bounds__(256) void k_prep(
    const float* __restrict__ sw0, const float* __restrict__ sg0, const float* __restrict__ sb0,
    const float* __restrict__ sw1, const float* __restrict__ sg1, const float* __restrict__ sb1,
    const float* __restrict__ sw2, const float* __restrict__ sbias2,
    const float* __restrict__ pw0, const float* __restrict__ pg0, const float* __restrict__ pb0,
    const float* __restrict__ pw1, const float* __restrict__ pg1, const float* __restrict__ pb1,
    const float* __restrict__ pw2, const float* __restrict__ pbias2,
    float* __restrict__ wbuf)
{
    const int t = threadIdx.x;
    const float rs = rsqrtf(1.0f + EPS);
    if (t < 128) {
        wbuf[t]                 = pw0[t] * pg0[t >> 3] * rs;
        wbuf[128 + t]           = pw1[t] * pg1[t >> 4] * rs;
        wbuf[WSTRIDE + t]       = sw0[t] * sg0[t >> 3] * rs;
        wbuf[WSTRIDE + 128 + t] = sw1[t] * sg1[t >> 4] * rs;
    } else {
        const int u = t - 128;
        if (u < 8) {
            wbuf[256 + u] = pw2[u];
            wbuf[WSTRIDE + 256 + u] = sw2[u];
        } else if (u < 24) {
            wbuf[264 + (u - 8)] = pb0[u - 8];
            wbuf[WSTRIDE + 264 + (u - 8)] = sb0[u - 8];
        } else if (u < 32) {
            wbuf[280 + (u - 24)] = pb1[u - 24];
            wbuf[WSTRIDE + 280 + (u - 24)] = sb1[u - 24];
        } else if (u == 32) {
            wbuf[288] = pbias2[0];
            wbuf[WSTRIDE + 288] = sbias2[0];
        }
    }
}

// ---------------------------------------------------------------------------
// float2 / float4 helpers
// ---------------------------------------------------------------------------
__device__ __forceinline__ float2 relu2_(float2 a) {
    return make_float2(fmaxf(a.x, 0.f), fmaxf(a.y, 0.f));
}
__device__ __forceinline__ void fma2_(float s, const float2& v, float2& a) {
    a.x = fmaf(s, v.x, a.x); a.y = fmaf(s, v.y, a.y);
}
__device__ __forceinline__ float4 relu4_(float4 a) {
    return make_float4(fmaxf(a.x, 0.f), fmaxf(a.y, 0.f), fmaxf(a.z, 0.f), fmaxf(a.w, 0.f));
}
__device__ __forceinline__ void fma4_(float s, const float4& v, float4& a) {
    a.x = fmaf(s, v.x, a.x); a.y = fmaf(s, v.y, a.y);
    a.z = fmaf(s, v.z, a.z); a.w = fmaf(s, v.w, a.w);
}

// 2-pixel MLP, weights via wave-uniform global loads
__device__ __forceinline__ float2 mlp2g_(const float* __restrict__ Wb, const float2 x[8])
{
    const float4* __restrict__ W0 = (const float4*)(Wb);
    const float4* __restrict__ W1 = (const float4*)(Wb + 128);
    const float4* __restrict__ W2 = (const float4*)(Wb + 256);
    const float* __restrict__ B0 = Wb + 264;
    const float* __restrict__ B1 = Wb + 280;
    const float bias2 = Wb[288];

    float2 l1[16];
    #pragma unroll
    for (int o = 0; o < 16; ++o) {
        const float4 wa = W0[o * 2 + 0];
        const float4 wb = W0[o * 2 + 1];
        const float bb = B0[o];
        float2 a = make_float2(bb, bb);
        fma2_(wa.x, x[0], a); fma2_(wa.y, x[1], a);
        fma2_(wa.z, x[2], a); fma2_(wa.w, x[3], a);
        fma2_(wb.x, x[4], a); fma2_(wb.y, x[5], a);
        fma2_(wb.z, x[6], a); fma2_(wb.w, x[7], a);
        l1[o] = relu2_(a);
    }
    float2 l2[8];
    #pragma unroll
    for (int o = 0; o < 8; ++o) {
        const float bb = B1[o];
        float2 a = make_float2(bb, bb);
        #pragma unroll
        for (int c4 = 0; c4 < 4; ++c4) {
            const float4 w = W1[o * 4 + c4];
            fma2_(w.x, l1[c4 * 4 + 0], a); fma2_(w.y, l1[c4 * 4 + 1], a);
            fma2_(w.z, l1[c4 * 4 + 2], a); fma2_(w.w, l1[c4 * 4 + 3], a);
        }
        l2[o] = relu2_(a);
    }
    float2 h = make_float2(bias2, bias2);
    #pragma unroll
    for (int c4 = 0; c4 < 2; ++c4) {
        const float4 w = W2[c4];
        fma2_(w.x, l2[c4 * 4 + 0], h); fma2_(w.y, l2[c4 * 4 + 1], h);
        fma2_(w.z, l2[c4 * 4 + 2], h); fma2_(w.w, l2[c4 * 4 + 3], h);
    }
    return h;
}

// 4-pixel MLP, weights via wave-uniform global loads
__device__ __forceinline__ float4 mlp4g_(const float* __restrict__ Wb, const float4 x[8])
{
    const float4* __restrict__ W0 = (const float4*)(Wb);
    const float4* __restrict__ W1 = (const float4*)(Wb + 128);
    const float4* __restrict__ W2 = (const float4*)(Wb + 256);
    const float* __restrict__ B0 = Wb + 264;
    const float* __restrict__ B1 = Wb + 280;
    const float bias2 = Wb[288];

    float4 l1[16];
    #pragma unroll
    for (int o = 0; o < 16; ++o) {
        const float4 wa = W0[o * 2 + 0];
        const float4 wb = W0[o * 2 + 1];
        const float bb = B0[o];
        float4 a = make_float4(bb, bb, bb, bb);
        fma4_(wa.x, x[0], a); fma4_(wa.y, x[1], a);
        fma4_(wa.z, x[2], a); fma4_(wa.w, x[3], a);
        fma4_(wb.x, x[4], a); fma4_(wb.y, x[5], a);
        fma4_(wb.z, x[6], a); fma4_(wb.w, x[7], a);
        l1[o] = relu4_(a);
    }
    float4 l2[8];
    #pragma unroll
    for (int o = 0; o < 8; ++o) {
        const float bb = B1[o];
        float4 a = make_float4(bb, bb, bb, bb);
        #pragma unroll
        for (int c4 = 0; c4 < 4; ++c4) {
            const float4 w = W1[o * 4 + c4];
            fma4_(w.x, l1[c4 * 4 + 0], a); fma4_(w.y, l1[c4 * 4 + 1], a);
            fma4_(w.z, l1[c4 * 4 + 2], a); fma4_(w.w, l1[c4 * 4 + 3], a);
        }
        l2[o] = relu4_(a);
    }
    float4 h = make_float4(bias2, bias2, bias2, bias2);
    #pragma unroll
    for (int c4 = 0; c4 < 2; ++c4) {
        const float4 w = W2[c4];
        fma4_(w.x, l2[c4 * 4 + 0], h); fma4_(w.y, l2[c4 * 4 + 1], h);
        fma4_(w.z, l2[c4 * 4 + 2], h); fma4_(w.w, l2[c4 * 4 + 3], h);
    }
    return h;
}

// ---------------------------------------------------------------------------
// Variant A: 2 pixels/thread. Block = 16 depths x 16 pixel-pairs = 32 px.
// Live set ~48 VGPR -> no spills at default (64-VGPR) allocation.
// ---------------------------------------------------------------------------
__global__ __launch_bounds__(256) void k_fused2(
    const float* __restrict__ x1,
    const float* __restrict__ depth_sample,
    const float* __restrict__ depth_min, const float* __restrict__ depth_max,
    const float* __restrict__ wP, const float* __restrict__ wS,
    float* __restrict__ s_out, float* __restrict__ xn_out, int base)
{
    __shared__ float2 red[16][16];

    const int tid = threadIdx.x;
    const int q = tid & 15;
    const int dt = tid >> 4;
    const int pid0 = base + blockIdx.x * 32 + q * 2;
    const int b = pid0 / HW;
    const int p0 = pid0 - b * HW;

    const float* xp = x1 + ((size_t)(b * G * D) + dt) * HW + p0;
    float2 xq[8];
    #pragma unroll
    for (int g = 0; g < 8; ++g)
        xq[g] = *reinterpret_cast<const float2*>(xp + (size_t)g * D * HW);

    red[dt][q] = mlp2g_(wP, xq);
    __syncthreads();

    float2 mx = red[0][q];
    #pragma unroll
    for (int k = 1; k < 16; ++k) {
        const float2 r = red[k][q];
        mx.x = fmaxf(mx.x, r.x); mx.y = fmaxf(mx.y, r.y);
    }
    const float2 vw = make_float2(sigmoidf_(mx.x), sigmoidf_(mx.y));

    #pragma unroll
    for (int g = 0; g < 8; ++g) { xq[g].x *= vw.x; xq[g].y *= vw.y; }
    const float2 hS = mlp2g_(wS, xq);

    const size_t oidx = (size_t)(b * D + dt) * HW + p0;
    *reinterpret_cast<float2*>(s_out + oidx) = hS;

    const float inv_min = 1.0f / depth_min[b];
    const float inv_max = 1.0f / depth_max[b];
    const float rinv = 1.0f / (inv_min - inv_max);
    const float2 ds = *reinterpret_cast<const float2*>(depth_sample + oidx);
    *reinterpret_cast<float2*>(xn_out + oidx) =
        make_float2((1.0f / ds.x - inv_max) * rinv,
                    (1.0f / ds.y - inv_max) * rinv);
}

// ---------------------------------------------------------------------------
// Variant B: 4 pixels/thread with launch_bounds(256,1) -> VGPR free to grow
// past 64 (no scratch), at the cost of occupancy.
// ---------------------------------------------------------------------------
__global__ __launch_bounds__(256, 1) void k_fused4(
    const float* __restrict__ x1,
    const float* __restrict__ depth_sample,
    const float* __restrict__ depth_min, const float* __restrict__ depth_max,
    const float* __restrict__ wP, const float* __restrict__ wS,
    float* __restrict__ s_out, float* __restrict__ xn_out, int base)
{
    __shared__ float4 red[16][16];

    const int tid = threadIdx.x;
    const int q = tid & 15;
    const int dt = tid >> 4;
    const int pid0 = base + blockIdx.x * 64 + q * 4;
    const int b = pid0 / HW;
    const int p0 = pid0 - b * HW;

    const float* xp = x1 + ((size_t)(b * G * D) + dt) * HW + p0;
    float4 xq[8];
    #pragma unroll
    for (int g = 0; g < 8; ++g)
        xq[g] = *reinterpret_cast<const float4*>(xp + (size_t)g * D * HW);

    red[dt][q] = mlp4g_(wP, xq);
    __syncthreads();

    float4 mx = red[0][q];
    #pragma unroll
    for (int k = 1; k < 16; ++k) {
        const float4 r = red[k][q];
        mx.x = fmaxf(mx.x, r.x); mx.y = fmaxf(mx.y, r.y);
        mx.z = fmaxf(mx.z, r.z); mx.w = fmaxf(mx.w, r.w);
    }
    const float4 vw = make_float4(sigmoidf_(mx.x), sigmoidf_(mx.y),
                                  sigmoidf_(mx.z), sigmoidf_(mx.w));

    #pragma unroll
    for (int g = 0; g < 8; ++g) {
        xq[g].x *= vw.x; xq[g].y *= vw.y; xq[g].z *= vw.z; xq[g].w *= vw.w;
    }
    const float4 hS = mlp4g_(wS, xq);

    const size_t oidx = (size_t)(b * D + dt) * HW + p0;
    *reinterpret_cast<float4*>(s_out + oidx) = hS;

    const float inv_min = 1.0f / depth_min[b];
    const float inv_max = 1.0f / depth_max[b];
    const float rinv = 1.0f / (inv_min - inv_max);
    const float4 ds = *reinterpret_cast<const float4*>(depth_sample + oidx);
    *reinterpret_cast<float4*>(xn_out + oidx) =
        make_float4((1.0f / ds.x - inv_max) * rinv,
                    (1.0f / ds.y - inv_max) * rinv,
                    (1.0f / ds.z - inv_max) * rinv,
                    (1.0f / ds.w - inv_max) * rinv);
}

// ---------------------------------------------------------------------------
// Kernel: neighbor gathers on s and xn, dw, score, softmax over D, depth.
// (unchanged)
// ---------------------------------------------------------------------------
__global__ __launch_bounds__(256) void k_score_depth(
    const float* __restrict__ s_arr, const float* __restrict__ xn,
    const float* __restrict__ offset, const float* __restrict__ depth_sample,
    float* __restrict__ out)
{
    __shared__ float off_lds[18][64];
    __shared__ float redA[4][64];
    __shared__ float redB[4][64];

    const int tid = threadIdx.x;
    const int pi = tid & 63;
    const int slot = tid >> 6;
    const int pg0_ = blockIdx.x * 64;
    const int b = pg0_ / HW;
    const int pb0 = pg0_ - b * HW;
    const int p = pb0 + pi;
    const int h = p / W;
    const int w = p - h * W;

    const float* ob = offset + (size_t)b * 18 * HW + pb0;
    for (int idx = tid; idx < 18 * 64; idx += 256) {
        const int s = idx >> 6, qq = idx & 63;
        off_lds[s][qq] = ob[(size_t)s * HW + qq];
    }
    __syncthreads();

    int a1s[9], a2s[9];
    {
        int ry1[3], ry2[3], cx1[3], cx2[3];
        #pragma unroll
        for (int i = 0; i < 3; ++i) {
            ry1[i] = reflect_(h + (i - 1) * 2, H) * W;
            ry2[i] = reflect_(h + (i - 1) * 4, H) * W;
            cx1[i] = reflect_(w + (i - 1) * 2, W);
            cx2[i] = reflect_(w + (i - 1) * 4, W);
        }
        #pragma unroll
        for (int s = 0; s < 9; ++s) {
            a1s[s] = ry1[s / 3] + cx1[s % 3];
            a2s[s] = ry2[s / 3] + cx2[s % 3];
        }
    }

    const size_t bbase = (size_t)b * D * HW;

    float score[4], dsv[4];
    #pragma unroll
    for (int i = 0; i < 4; ++i) {
        const int d = slot * 4 + i;
        const float* sd = s_arr + bbase + (size_t)d * HW;
        const float* xd = xn + bbase + (size_t)d * HW;
        float accs = 0.0f, accx = 0.0f;
        #pragma unroll
        for (int s = 0; s < 9; ++s) {
            const float w1 = off_lds[s + 9][pi];
            const float w2 = off_lds[s][pi];
            accs += 0.5f * (w1 * sd[a1s[s]] + w2 * sd[a2s[s]]);
            accx += 0.5f * (w1 * xd[a1s[s]] + w2 * xd[a2s[s]]);
        }
        const float xc = xd[p];
        const float diff = fminf(fabsf(accx - xc) * 40.0f, 4.0f);
        const float dwv = sigmoidf_((2.0f - diff) * 2.0f);
        score[i] = accs * dwv;
        dsv[i] = depth_sample[bbase + (size_t)d * HW + p];
    }

    float mp = fmaxf(fmaxf(score[0], score[1]), fmaxf(score[2], score[3]));
    redA[slot][pi] = mp;
    __syncthreads();
    const float m = fmaxf(fmaxf(redA[0][pi], redA[1][pi]),
                          fmaxf(redA[2][pi], redA[3][pi]));
    float sp = 0.0f, ap = 0.0f;
    #pragma unroll
    for (int i = 0; i < 4; ++i) {
        const float e = __expf(score[i] - m);
        sp += e;
        ap = fmaf(dsv[i], e, ap);
    }
    __syncthreads();
    redA[slot][pi] = sp;
    redB[slot][pi] = ap;
    __syncthreads();
    if (slot == 0) {
        const float sum = redA[0][pi] + redA[1][pi] + redA[2][pi] + redA[3][pi];
        const float acc = redB[0][pi] + redB[1][pi] + redB[2][pi] + redB[3][pi];
        out[pg0_ + pi] = acc / sum;
    }
}

// ---------------------------------------------------------------------------
extern "C" void kernel_launch(void* const* d_in, const int* in_sizes, int n_in,
                              void* d_out, int out_size, void* d_ws, size_t ws_size,
                              hipStream_t stream)
{
    const float* x1           = (const float*)d_in[0];
    const float* offset       = (const float*)d_in[1];
    const float* depth_sample = (const float*)d_in[2];
    const float* depth_min    = (const float*)d_in[3];
    const float* depth_max    = (const float*)d_in[4];
    const float* s_w0 = (const float*)d_in[5];
    const float* s_g0 = (const float*)d_in[6];
    const float* s_b0 = (const float*)d_in[7];
    const float* s_w1 = (const float*)d_in[8];
    const float* s_g1 = (const float*)d_in[9];
    const float* s_b1 = (const float*)d_in[10];
    const float* s_w2 = (const float*)d_in[11];
    const float* s_bias2 = (const float*)d_in[12];
    const float* p_w0 = (const float*)d_in[13];
    const float* p_g0 = (const float*)d_in[14];
    const float* p_b0 = (const float*)d_in[15];
    const float* p_w1 = (const float*)d_in[16];
    const float* p_g1 = (const float*)d_in[17];
    const float* p_b1 = (const float*)d_in[18];
    const float* p_w2 = (const float*)d_in[19];
    const float* p_bias2 = (const float*)d_in[20];

    float* s_arr = (float*)d_ws;                         // B*D*HW
    float* xn    = s_arr + (size_t)B * D * HW;           // B*D*HW
    float* wbuf  = xn + (size_t)B * D * HW;              // 2*WSTRIDE floats

    k_prep<<<1, 256, 0, stream>>>(
        s_w0, s_g0, s_b0, s_w1, s_g1, s_b1, s_w2, s_bias2,
        p_w0, p_g0, p_b0, p_w1, p_g1, p_b1, p_w2, p_bias2, wbuf);

    const int half = (B * HW) / 2;   // = HW: variant A handles batch 0

    k_fused2<<<half / 32, 256, 0, stream>>>(
        x1, depth_sample, depth_min, depth_max,
        wbuf, wbuf + WSTRIDE, s_arr, xn, 0);

    k_fused4<<<half / 64, 256, 0, stream>>>(
        x1, depth_sample, depth_min, depth_max,
        wbuf, wbuf + WSTRIDE, s_arr, xn, half);

    k_score_depth<<<(B * HW) / 64, 256, 0, stream>>>(
        s_arr, xn, offset, depth_sample, (float*)d_out);
}

// Round 8
// 82.963 us; speedup vs baseline: 1.3089x; 1.3089x over previous
//
#include <hip/hip_runtime.h>
#include <math.h>

// Problem constants (fixed by the reference's setup_inputs)
constexpr int B = 2, G = 8, D = 16, H = 256, W = 320;
constexpr int HW = H * W;
constexpr float EPS = 1e-5f;
constexpr int WSTRIDE = 320;   // floats per folded-weight block (P at 0, S at 320)

__device__ __forceinline__ float sigmoidf_(float x) {
    return 1.0f / (1.0f + __expf(-x));
}

__device__ __forceinline__ int reflect_(int i, int n) {
    return i < 0 ? -i : (i >= n ? 2 * n - 2 - i : i);
}

// ---------------------------------------------------------------------------
// k_prep: fold BN (gamma / sqrt(1+eps)) into weights, pack into d_ws.
// Layout per net (stride WSTRIDE): W0f[0:128) W1f[128:256) W2[256:264)
// B0[264:280) B1[280:288) bias2[288].
// ---------------------------------------------------------------------------
__global__ __launch_bounds__(256) void k_prep(
    const float* __restrict__ sw0, const float* __restrict__ sg0, const float* __restrict__ sb0,
    const float* __restrict__ sw1, const float* __restrict__ sg1, const float* __restrict__ sb1,
    const float* __restrict__ sw2, const float* __restrict__ sbias2,
    const float* __restrict__ pw0, const float* __restrict__ pg0, const float* __restrict__ pb0,
    const float* __restrict__ pw1, const float* __restrict__ pg1, const float* __restrict__ pb1,
    const float* __restrict__ pw2, const float* __restrict__ pbias2,
    float* __restrict__ wbuf)
{
    const int t = threadIdx.x;
    const float rs = rsqrtf(1.0f + EPS);
    if (t < 128) {
        wbuf[t]                 = pw0[t] * pg0[t >> 3] * rs;
        wbuf[128 + t]           = pw1[t] * pg1[t >> 4] * rs;
        wbuf[WSTRIDE + t]       = sw0[t] * sg0[t >> 3] * rs;
        wbuf[WSTRIDE + 128 + t] = sw1[t] * sg1[t >> 4] * rs;
    } else {
        const int u = t - 128;
        if (u < 8) {
            wbuf[256 + u] = pw2[u];
            wbuf[WSTRIDE + 256 + u] = sw2[u];
        } else if (u < 24) {
            wbuf[264 + (u - 8)] = pb0[u - 8];
            wbuf[WSTRIDE + 264 + (u - 8)] = sb0[u - 8];
        } else if (u < 32) {
            wbuf[280 + (u - 24)] = pb1[u - 24];
            wbuf[WSTRIDE + 280 + (u - 24)] = sb1[u - 24];
        } else if (u == 32) {
            wbuf[288] = pbias2[0];
            wbuf[WSTRIDE + 288] = sbias2[0];
        }
    }
}

// ---------------------------------------------------------------------------
// Scalar (1-pixel) MLP 8->16(ReLU)->8(ReLU)->1. All weight indices are
// compile-time constants with a wave-uniform base -> scalar s_load broadcast,
// zero DS traffic, ~1 SGPR operand per v_fma. Live set ~40 VGPR.
// ---------------------------------------------------------------------------
__device__ __forceinline__ float mlpg_(const float* __restrict__ Wb, const float x[8])
{
    float l1[16];
    #pragma unroll
    for (int o = 0; o < 16; ++o) {
        float a = Wb[264 + o];
        #pragma unroll
        for (int c = 0; c < 8; ++c) a = fmaf(Wb[o * 8 + c], x[c], a);
        l1[o] = fmaxf(a, 0.0f);
    }
    float l2[8];
    #pragma unroll
    for (int o = 0; o < 8; ++o) {
        float a = Wb[280 + o];
        #pragma unroll
        for (int c = 0; c < 16; ++c) a = fmaf(Wb[128 + o * 16 + c], l1[c], a);
        l2[o] = fmaxf(a, 0.0f);
    }
    float h = Wb[288];
    #pragma unroll
    for (int c = 0; c < 8; ++c) h = fmaf(Wb[256 + c], l2[c], h);
    return h;
}

// ---------------------------------------------------------------------------
// Fused: PixelwiseNet + max-over-D + SimilarityNet, ONE read of x1.
// Block = 1024 threads = 64 consecutive pixels x 16 depths, one (pixel,depth)
// per thread. Weights via wave-uniform global loads. launch_bounds(1024,8)
// caps VGPR at 64 -> 2 blocks (32 waves)/CU for max latency hiding.
// ---------------------------------------------------------------------------
__global__ __launch_bounds__(1024, 8) void k_fused(
    const float* __restrict__ x1,
    const float* __restrict__ depth_sample,
    const float* __restrict__ depth_min, const float* __restrict__ depth_max,
    const float* __restrict__ wP, const float* __restrict__ wS,
    float* __restrict__ s_out, float* __restrict__ xn_out)
{
    __shared__ float red[16][64];

    const int tid = threadIdx.x;
    const int pi = tid & 63;          // pixel lane (64 consecutive)
    const int dt = tid >> 6;          // depth hypothesis 0..15
    const int pid = blockIdx.x * 64 + pi;   // global pixel over B*HW
    const int b = pid / HW;
    const int p = pid - b * HW;

    // ---- load this thread's 8 group values (256B wave-contiguous) ----
    const float* xp = x1 + ((size_t)(b * G * D) + dt) * HW + p;
    float x[8];
    #pragma unroll
    for (int g = 0; g < 8; ++g) x[g] = xp[(size_t)g * D * HW];

    // ---- PixelwiseNet head (sigmoid deferred; monotone) ----
    red[dt][pi] = mlpg_(wP, x);
    __syncthreads();

    // ---- max over 16 depth hypotheses for this pixel ----
    float mx = red[0][pi];
    #pragma unroll
    for (int k = 1; k < 16; ++k) mx = fmaxf(mx, red[k][pi]);
    const float vw = sigmoidf_(mx);

    // ---- SimilarityNet on x * vw (reuse registers) ----
    #pragma unroll
    for (int g = 0; g < 8; ++g) x[g] *= vw;
    const float hS = mlpg_(wS, x);

    const size_t oidx = (size_t)(b * D + dt) * HW + p;
    s_out[oidx] = hS;

    // ---- normalized inverse depth ----
    const float inv_min = 1.0f / depth_min[b];
    const float inv_max = 1.0f / depth_max[b];
    const float rinv = 1.0f / (inv_min - inv_max);
    const float ds = depth_sample[oidx];
    xn_out[oidx] = (1.0f / ds - inv_max) * rinv;
}

// ---------------------------------------------------------------------------
// k_score_depth: Block = 1024 threads = 64 px x 16 depths, ONE depth/thread
// (20 loads each -> 4x TLP vs 4-depth threads). Bijective XCD swizzle keeps
// adjacent blocks (sharing tap rows) on the same XCD's L2.
// ---------------------------------------------------------------------------
__global__ __launch_bounds__(1024, 8) void k_score_depth(
    const float* __restrict__ s_arr, const float* __restrict__ xn,
    const float* __restrict__ offset, const float* __restrict__ depth_sample,
    float* __restrict__ out)
{
    __shared__ float off_lds[18][64];
    __shared__ float redM[16][64];
    __shared__ float redS[16][64];
    __shared__ float redA[16][64];

    // bijective XCD swizzle: nwg = 2560 = 8 * 320
    const int bid = blockIdx.x;
    const int wg = (bid & 7) * 320 + (bid >> 3);

    const int tid = threadIdx.x;
    const int pi = tid & 63;
    const int dt = tid >> 6;
    const int pg0_ = wg * 64;              // first global pixel of block
    const int b = pg0_ / HW;
    const int pb0 = pg0_ - b * HW;
    const int p = pb0 + pi;
    const int h = p / W;
    const int w = p - h * W;

    // ---- stage per-pixel neighbor weights ----
    const float* ob = offset + (size_t)b * 18 * HW + pb0;
    for (int idx = tid; idx < 18 * 64; idx += 1024) {
        const int s = idx >> 6, qq = idx & 63;
        off_lds[s][qq] = ob[(size_t)s * HW + qq];
    }
    __syncthreads();

    // ---- reflected tap indices (depth-invariant) ----
    int a1s[9], a2s[9];
    {
        int ry1[3], ry2[3], cx1[3], cx2[3];
        #pragma unroll
        for (int i = 0; i < 3; ++i) {
            ry1[i] = reflect_(h + (i - 1) * 2, H) * W;
            ry2[i] = reflect_(h + (i - 1) * 4, H) * W;
            cx1[i] = reflect_(w + (i - 1) * 2, W);
            cx2[i] = reflect_(w + (i - 1) * 4, W);
        }
        #pragma unroll
        for (int s = 0; s < 9; ++s) {
            a1s[s] = ry1[s / 3] + cx1[s % 3];
            a2s[s] = ry2[s / 3] + cx2[s % 3];
        }
    }

    const size_t bbase = (size_t)b * D * HW;
    const float* sd = s_arr + bbase + (size_t)dt * HW;
    const float* xd = xn + bbase + (size_t)dt * HW;

    float accs = 0.0f, accx = 0.0f;
    #pragma unroll
    for (int s = 0; s < 9; ++s) {
        const float w1 = off_lds[s + 9][pi];   // dilation-2 (X1) weight
        const float w2 = off_lds[s][pi];       // dilation-4 (X2) weight
        accs += 0.5f * (w1 * sd[a1s[s]] + w2 * sd[a2s[s]]);
        accx += 0.5f * (w1 * xd[a1s[s]] + w2 * xd[a2s[s]]);
    }
    const float xc = xd[p];
    const float diff = fminf(fabsf(accx - xc) * 40.0f, 4.0f);  // /0.025, clip 4
    const float dwv = sigmoidf_((2.0f - diff) * 2.0f);
    const float score = accs * dwv;
    const float dsv = depth_sample[bbase + (size_t)dt * HW + p];

    // ---- softmax over 16 depths via LDS ----
    redM[dt][pi] = score;
    __syncthreads();
    float m = redM[0][pi];
    #pragma unroll
    for (int k = 1; k < 16; ++k) m = fmaxf(m, redM[k][pi]);

    const float e = __expf(score - m);
    redS[dt][pi] = e;
    redA[dt][pi] = dsv * e;
    __syncthreads();

    if (dt == 0) {
        float sum = 0.0f, acc = 0.0f;
        #pragma unroll
        for (int k = 0; k < 16; ++k) { sum += redS[k][pi]; acc += redA[k][pi]; }
        out[pg0_ + pi] = acc / sum;
    }
}

// ---------------------------------------------------------------------------
extern "C" void kernel_launch(void* const* d_in, const int* in_sizes, int n_in,
                              void* d_out, int out_size, void* d_ws, size_t ws_size,
                              hipStream_t stream)
{
    const float* x1           = (const float*)d_in[0];
    const float* offset       = (const float*)d_in[1];
    const float* depth_sample = (const float*)d_in[2];
    const float* depth_min    = (const float*)d_in[3];
    const float* depth_max    = (const float*)d_in[4];
    const float* s_w0 = (const float*)d_in[5];
    const float* s_g0 = (const float*)d_in[6];
    const float* s_b0 = (const float*)d_in[7];
    const float* s_w1 = (const float*)d_in[8];
    const float* s_g1 = (const float*)d_in[9];
    const float* s_b1 = (const float*)d_in[10];
    const float* s_w2 = (const float*)d_in[11];
    const float* s_bias2 = (const float*)d_in[12];
    const float* p_w0 = (const float*)d_in[13];
    const float* p_g0 = (const float*)d_in[14];
    const float* p_b0 = (const float*)d_in[15];
    const float* p_w1 = (const float*)d_in[16];
    const float* p_g1 = (const float*)d_in[17];
    const float* p_b1 = (const float*)d_in[18];
    const float* p_w2 = (const float*)d_in[19];
    const float* p_bias2 = (const float*)d_in[20];

    float* s_arr = (float*)d_ws;                         // B*D*HW
    float* xn    = s_arr + (size_t)B * D * HW;           // B*D*HW
    float* wbuf  = xn + (size_t)B * D * HW;              // 2*WSTRIDE floats

    k_prep<<<1, 256, 0, stream>>>(
        s_w0, s_g0, s_b0, s_w1, s_g1, s_b1, s_w2, s_bias2,
        p_w0, p_g0, p_b0, p_w1, p_g1, p_b1, p_w2, p_bias2, wbuf);

    k_fused<<<(B * HW) / 64, 1024, 0, stream>>>(
        x1, depth_sample, depth_min, depth_max,
        wbuf, wbuf + WSTRIDE, s_arr, xn);

    k_score_depth<<<(B * HW) / 64, 1024, 0, stream>>>(
        s_arr, xn, offset, depth_sample, (float*)d_out);
}

// Round 9
// 71.836 us; speedup vs baseline: 1.5116x; 1.1549x over previous
//
#include <hip/hip_runtime.h>
#include <math.h>

// Problem constants (fixed by the reference's setup_inputs)
constexpr int B = 2, G = 8, D = 16, H = 256, W = 320;
constexpr int HW = H * W;
constexpr float EPS = 1e-5f;
constexpr int WSTRIDE = 320;   // floats per folded-weight block (P at 0, S at WSTRIDE)

typedef _Float16 h2 __attribute__((ext_vector_type(2)));

#if __has_builtin(__builtin_amdgcn_fdot2)
#define FDOT2(a, b, c) __builtin_amdgcn_fdot2((a), (b), (c), false)
#else
#define FDOT2(a, b, c) fmaf((float)(a).x, (float)(b).x, fmaf((float)(a).y, (float)(b).y, (c)))
#endif

__device__ __forceinline__ float sigmoidf_(float x) {
    return 1.0f / (1.0f + __expf(-x));
}

__device__ __forceinline__ int reflect_(int i, int n) {
    return i < 0 ? -i : (i >= n ? 2 * n - 2 - i : i);
}

// ---------------------------------------------------------------------------
// k_prep: fold BN into weights and pack as f16 pairs (h2) for v_dot2.
// Layout per net (float-slot stride WSTRIDE):
//   h2 W0h[64]  at slots [0,64)    : 16 outputs x 4 pairs (8 in-ch)
//   h2 W1h[64]  at slots [64,128)  : 8 outputs x 8 pairs (16 in-ch)
//   h2 W2h[4]   at slots [128,132) : 1 output x 4 pairs (8 in-ch)
//   f32 B0[16]  at [132,148), B1[8] at [148,156), bias2 at [156]
// ---------------------------------------------------------------------------
__device__ __forceinline__ void pack_net_(
    const float* __restrict__ w0, const float* __restrict__ g0, const float* __restrict__ b0,
    const float* __restrict__ w1, const float* __restrict__ g1, const float* __restrict__ b1,
    const float* __restrict__ w2, const float* __restrict__ bias2,
    float* __restrict__ o, int t, float rs)
{
    if (t < 64) {                      // W0: out = t>>2, pair = t&3
        const int oo = t >> 2, j = t & 3;
        const float s = g0[oo] * rs;
        h2 v; v.x = (_Float16)(w0[oo * 8 + 2 * j] * s);
        v.y = (_Float16)(w0[oo * 8 + 2 * j + 1] * s);
        ((h2*)o)[t] = v;
    } else if (t < 128) {              // W1: out = u>>3, pair = u&7
        const int u = t - 64, oo = u >> 3, j = u & 7;
        const float s = g1[oo] * rs;
        h2 v; v.x = (_Float16)(w1[oo * 16 + 2 * j] * s);
        v.y = (_Float16)(w1[oo * 16 + 2 * j + 1] * s);
        ((h2*)o)[t] = v;
    } else if (t < 132) {              // W2: 4 pairs
        const int u = t - 128;
        h2 v; v.x = (_Float16)w2[2 * u];
        v.y = (_Float16)w2[2 * u + 1];
        ((h2*)o)[t] = v;
    } else if (t < 148) {
        o[t] = b0[t - 132];
    } else if (t < 156) {
        o[t] = b1[t - 148];
    } else if (t == 156) {
        o[t] = bias2[0];
    }
}

__global__ __launch_bounds__(256) void k_prep(
    const float* __restrict__ sw0, const float* __restrict__ sg0, const float* __restrict__ sb0,
    const float* __restrict__ sw1, const float* __restrict__ sg1, const float* __restrict__ sb1,
    const float* __restrict__ sw2, const float* __restrict__ sbias2,
    const float* __restrict__ pw0, const float* __restrict__ pg0, const float* __restrict__ pb0,
    const float* __restrict__ pw1, const float* __restrict__ pg1, const float* __restrict__ pb1,
    const float* __restrict__ pw2, const float* __restrict__ pbias2,
    float* __restrict__ wbuf)
{
    const int t = threadIdx.x;
    const float rs = rsqrtf(1.0f + EPS);
    pack_net_(pw0, pg0, pb0, pw1, pg1, pb1, pw2, pbias2, wbuf, t, rs);
    pack_net_(sw0, sg0, sb0, sw1, sg1, sb1, sw2, sbias2, wbuf + WSTRIDE, t, rs);
}

// ---------------------------------------------------------------------------
// MLP 8->16(ReLU)->8(ReLU)->1 via packed-f16 dot2 (f32 accumulate).
// Weight fetches are wave-uniform (scalar broadcast); 132 dot2 per call.
// ---------------------------------------------------------------------------
__device__ __forceinline__ float mlph_(const float* __restrict__ Wb, const h2 xh[4])
{
    const h2* __restrict__ W0 = (const h2*)Wb;          // 64
    const h2* __restrict__ W1 = (const h2*)Wb + 64;     // 64
    const h2* __restrict__ W2 = (const h2*)Wb + 128;    // 4
    const float* __restrict__ B0 = Wb + 132;
    const float* __restrict__ B1 = Wb + 148;

    float l1[16];
    #pragma unroll
    for (int o = 0; o < 16; ++o) {
        float a = B0[o];
        #pragma unroll
        for (int j = 0; j < 4; ++j) a = FDOT2(W0[o * 4 + j], xh[j], a);
        l1[o] = fmaxf(a, 0.0f);
    }
    h2 l1h[8];
    #pragma unroll
    for (int j = 0; j < 8; ++j) {
        h2 v; v.x = (_Float16)l1[2 * j]; v.y = (_Float16)l1[2 * j + 1];
        l1h[j] = v;
    }
    float l2[8];
    #pragma unroll
    for (int o = 0; o < 8; ++o) {
        float a = B1[o];
        #pragma unroll
        for (int j = 0; j < 8; ++j) a = FDOT2(W1[o * 8 + j], l1h[j], a);
        l2[o] = fmaxf(a, 0.0f);
    }
    h2 l2h[4];
    #pragma unroll
    for (int j = 0; j < 4; ++j) {
        h2 v; v.x = (_Float16)l2[2 * j]; v.y = (_Float16)l2[2 * j + 1];
        l2h[j] = v;
    }
    float h = Wb[156];
    #pragma unroll
    for (int j = 0; j < 4; ++j) h = FDOT2(W2[j], l2h[j], h);
    return h;
}

// ---------------------------------------------------------------------------
// Fused: PixelwiseNet + max-over-D + SimilarityNet, ONE read of x1.
// Block = 1024 threads = 64 consecutive pixels x 16 depths, one (pixel,depth)
// per thread. x kept as 4x h2 across the barrier (~tiny live set). S-net
// input = xh * vw via packed f16 mul.
// ---------------------------------------------------------------------------
__global__ __launch_bounds__(1024, 8) void k_fused(
    const float* __restrict__ x1,
    const float* __restrict__ depth_sample,
    const float* __restrict__ depth_min, const float* __restrict__ depth_max,
    const float* __restrict__ wP, const float* __restrict__ wS,
    float* __restrict__ s_out, float* __restrict__ xn_out)
{
    __shared__ float red[16][64];

    const int tid = threadIdx.x;
    const int pi = tid & 63;          // pixel lane (64 consecutive)
    const int dt = tid >> 6;          // depth hypothesis 0..15
    const int pid = blockIdx.x * 64 + pi;   // global pixel over B*HW
    const int b = pid / HW;
    const int p = pid - b * HW;

    // ---- load this thread's 8 group values (256B wave-contiguous), pack f16
    const float* xp = x1 + ((size_t)(b * G * D) + dt) * HW + p;
    float x[8];
    #pragma unroll
    for (int g = 0; g < 8; ++g) x[g] = xp[(size_t)g * D * HW];
    h2 xh[4];
    #pragma unroll
    for (int j = 0; j < 4; ++j) {
        h2 v; v.x = (_Float16)x[2 * j]; v.y = (_Float16)x[2 * j + 1];
        xh[j] = v;
    }

    // ---- PixelwiseNet head (sigmoid deferred; monotone) ----
    red[dt][pi] = mlph_(wP, xh);
    __syncthreads();

    // ---- max over 16 depth hypotheses for this pixel ----
    float mx = red[0][pi];
    #pragma unroll
    for (int k = 1; k < 16; ++k) mx = fmaxf(mx, red[k][pi]);
    const float vw = sigmoidf_(mx);

    // ---- SimilarityNet on xh * vw (packed f16 mul) ----
    h2 vwh; vwh.x = (_Float16)vw; vwh.y = (_Float16)vw;
    h2 xsh[4];
    #pragma unroll
    for (int j = 0; j < 4; ++j) xsh[j] = xh[j] * vwh;
    const float hS = mlph_(wS, xsh);

    const size_t oidx = (size_t)(b * D + dt) * HW + p;
    s_out[oidx] = hS;

    // ---- normalized inverse depth ----
    const float inv_min = 1.0f / depth_min[b];
    const float inv_max = 1.0f / depth_max[b];
    const float rinv = 1.0f / (inv_min - inv_max);
    const float ds = depth_sample[oidx];
    xn_out[oidx] = (1.0f / ds - inv_max) * rinv;
}

// ---------------------------------------------------------------------------
// k_score_depth: 1024 threads = 64 px x 16 depths, one depth/thread.
// Bijective XCD swizzle (nwg = 2560 = 8*320). (measured ~20 us, unchanged)
// ---------------------------------------------------------------------------
__global__ __launch_bounds__(1024, 8) void k_score_depth(
    const float* __restrict__ s_arr, const float* __restrict__ xn,
    const float* __restrict__ offset, const float* __restrict__ depth_sample,
    float* __restrict__ out)
{
    __shared__ float off_lds[18][64];
    __shared__ float redM[16][64];
    __shared__ float redS[16][64];
    __shared__ float redA[16][64];

    const int bid = blockIdx.x;
    const int wg = (bid & 7) * 320 + (bid >> 3);

    const int tid = threadIdx.x;
    const int pi = tid & 63;
    const int dt = tid >> 6;
    const int pg0_ = wg * 64;
    const int b = pg0_ / HW;
    const int pb0 = pg0_ - b * HW;
    const int p = pb0 + pi;
    const int h = p / W;
    const int w = p - h * W;

    const float* ob = offset + (size_t)b * 18 * HW + pb0;
    for (int idx = tid; idx < 18 * 64; idx += 1024) {
        const int s = idx >> 6, qq = idx & 63;
        off_lds[s][qq] = ob[(size_t)s * HW + qq];
    }
    __syncthreads();

    int a1s[9], a2s[9];
    {
        int ry1[3], ry2[3], cx1[3], cx2[3];
        #pragma unroll
        for (int i = 0; i < 3; ++i) {
            ry1[i] = reflect_(h + (i - 1) * 2, H) * W;
            ry2[i] = reflect_(h + (i - 1) * 4, H) * W;
            cx1[i] = reflect_(w + (i - 1) * 2, W);
            cx2[i] = reflect_(w + (i - 1) * 4, W);
        }
        #pragma unroll
        for (int s = 0; s < 9; ++s) {
            a1s[s] = ry1[s / 3] + cx1[s % 3];
            a2s[s] = ry2[s / 3] + cx2[s % 3];
        }
    }

    const size_t bbase = (size_t)b * D * HW;
    const float* sd = s_arr + bbase + (size_t)dt * HW;
    const float* xd = xn + bbase + (size_t)dt * HW;

    float accs = 0.0f, accx = 0.0f;
    #pragma unroll
    for (int s = 0; s < 9; ++s) {
        const float w1 = off_lds[s + 9][pi];
        const float w2 = off_lds[s][pi];
        accs += 0.5f * (w1 * sd[a1s[s]] + w2 * sd[a2s[s]]);
        accx += 0.5f * (w1 * xd[a1s[s]] + w2 * xd[a2s[s]]);
    }
    const float xc = xd[p];
    const float diff = fminf(fabsf(accx - xc) * 40.0f, 4.0f);
    const float dwv = sigmoidf_((2.0f - diff) * 2.0f);
    const float score = accs * dwv;
    const float dsv = depth_sample[bbase + (size_t)dt * HW + p];

    redM[dt][pi] = score;
    __syncthreads();
    float m = redM[0][pi];
    #pragma unroll
    for (int k = 1; k < 16; ++k) m = fmaxf(m, redM[k][pi]);

    const float e = __expf(score - m);
    redS[dt][pi] = e;
    redA[dt][pi] = dsv * e;
    __syncthreads();

    if (dt == 0) {
        float sum = 0.0f, acc = 0.0f;
        #pragma unroll
        for (int k = 0; k < 16; ++k) { sum += redS[k][pi]; acc += redA[k][pi]; }
        out[pg0_ + pi] = acc / sum;
    }
}

// ---------------------------------------------------------------------------
extern "C" void kernel_launch(void* const* d_in, const int* in_sizes, int n_in,
                              void* d_out, int out_size, void* d_ws, size_t ws_size,
                              hipStream_t stream)
{
    const float* x1           = (const float*)d_in[0];
    const float* offset       = (const float*)d_in[1];
    const float* depth_sample = (const float*)d_in[2];
    const float* depth_min    = (const float*)d_in[3];
    const float* depth_max    = (const float*)d_in[4];
    const float* s_w0 = (const float*)d_in[5];
    const float* s_g0 = (const float*)d_in[6];
    const float* s_b0 = (const float*)d_in[7];
    const float* s_w1 = (const float*)d_in[8];
    const float* s_g1 = (const float*)d_in[9];
    const float* s_b1 = (const float*)d_in[10];
    const float* s_w2 = (const float*)d_in[11];
    const float* s_bias2 = (const float*)d_in[12];
    const float* p_w0 = (const float*)d_in[13];
    const float* p_g0 = (const float*)d_in[14];
    const float* p_b0 = (const float*)d_in[15];
    const float* p_w1 = (const float*)d_in[16];
    const float* p_g1 = (const float*)d_in[17];
    const float* p_b1 = (const float*)d_in[18];
    const float* p_w2 = (const float*)d_in[19];
    const float* p_bias2 = (const float*)d_in[20];

    float* s_arr = (float*)d_ws;                         // B*D*HW
    float* xn    = s_arr + (size_t)B * D * HW;           // B*D*HW
    float* wbuf  = xn + (size_t)B * D * HW;              // 2*WSTRIDE floats

    k_prep<<<1, 256, 0, stream>>>(
        s_w0, s_g0, s_b0, s_w1, s_g1, s_b1, s_w2, s_bias2,
        p_w0, p_g0, p_b0, p_w1, p_g1, p_b1, p_w2, p_bias2, wbuf);

    k_fused<<<(B * HW) / 64, 1024, 0, stream>>>(
        x1, depth_sample, depth_min, depth_max,
        wbuf, wbuf + WSTRIDE, s_arr, xn);

    k_score_depth<<<(B * HW) / 64, 1024, 0, stream>>>(
        s_arr, xn, offset, depth_sample, (float*)d_out);
}